// Round 1
// baseline (295.159 us; speedup 1.0000x reference)
//
#include <hip/hip_runtime.h>

// DVQ bottleneck: B=8, N=4096, D=1024, S=4, K=16, d=256, BETA=0.25
// Outputs (flat fp32 in d_out): z[8*4096*1024], ids_packed[32768] (as float),
// vq_total[1].

#define D_FULL 1024
#define SEG 4
#define DSEG 256
#define KC 16
#define TPB_TOKENS 64   // tokens per block (one per lane; 4 waves = 4 segments)

// Prep: fp64 codebook copy + fp64 ||c||^2 per (s,k) into d_ws; zero loss slot
// (d_out is poisoned 0xAA before every timed launch).
__global__ __launch_bounds__(256) void dvq_prep(const float* __restrict__ cb,
                                                double* __restrict__ cbd,
                                                double* __restrict__ c2d,
                                                float* __restrict__ loss_out) {
    int i = threadIdx.x;
    for (int j = i; j < SEG * KC * DSEG; j += 256)
        cbd[j] = (double)cb[j];
    if (i < SEG * KC) {
        const float* p = cb + i * DSEG;
        double s = 0.0;
        for (int j = 0; j < DSEG; ++j) {
            double v = (double)p[j];
            s = fma(v, v, s);
        }
        c2d[i] = s;
    }
    if (i == 0) *loss_out = 0.0f;
}

__global__ __launch_bounds__(256) void dvq_main(const float* __restrict__ h,
                                                const float* __restrict__ cb,
                                                const double* __restrict__ cbd,
                                                const double* __restrict__ c2d,
                                                float* __restrict__ z_out,
                                                float* __restrict__ ids_out,
                                                float* __restrict__ loss_out) {
    __shared__ int ids_lds[TPB_TOKENS][SEG];
    __shared__ double red[4];

    const int i = threadIdx.x;
    const int lane = i & 63;
    const int w = i >> 6;                       // wave id == segment id
    const int s = __builtin_amdgcn_readfirstlane(w);  // force wave-uniform SGPR

    const long tok_base = (long)blockIdx.x * TPB_TOKENS;
    const long tok = tok_base + lane;

    // ---- Phase 1: fp64 scores for this lane's (token, segment) ----
    const float4* zp = (const float4*)(h + tok * D_FULL + (long)s * DSEG);
    const double* cbs = cbd + s * (KC * DSEG);  // uniform base -> s_load path

    double dot[KC];
#pragma unroll
    for (int k = 0; k < KC; ++k) dot[k] = 0.0;
    double ze2 = 0.0;

    for (int c = 0; c < DSEG / 4; ++c) {
        float4 z4 = zp[c];
        double z0 = (double)z4.x, z1 = (double)z4.y;
        double z2 = (double)z4.z, z3 = (double)z4.w;
        ze2 = fma(z0, z0, ze2);
        ze2 = fma(z1, z1, ze2);
        ze2 = fma(z2, z2, ze2);
        ze2 = fma(z3, z3, ze2);
#pragma unroll
        for (int k = 0; k < KC; ++k) {
            const double* ck = cbs + k * DSEG + c * 4;  // wave-uniform address
            double a = dot[k];
            a = fma(z0, ck[0], a);
            a = fma(z1, ck[1], a);
            a = fma(z2, ck[2], a);
            a = fma(z3, ck[3], a);
            dot[k] = a;
        }
    }

    // argmin over k; strict < keeps lowest k (jnp.argmin first-index tie-break)
    const double* c2s = c2d + s * KC;
    double best = c2s[0] - 2.0 * dot[0];
    int bk = 0;
#pragma unroll
    for (int k = 1; k < KC; ++k) {
        double sc = c2s[k] - 2.0 * dot[k];
        if (sc < best) { best = sc; bk = k; }
    }
    ids_lds[lane][w] = bk;

    // min distance = ||ze||^2 + ||c||^2 - 2 ze.c  (loss contribution)
    double mind = ze2 + best;
#pragma unroll
    for (int off = 32; off > 0; off >>= 1)
        mind += __shfl_down(mind, off, 64);
    if (lane == 0) red[w] = mind;

    __syncthreads();  // ids_lds + red visible to whole block

    if (i == 0) {
        double tot = red[0] + red[1] + red[2] + red[3];
        // vq_total = (1 + BETA) * sum(min_dist) / (B*N*d)
        atomicAdd(loss_out, (float)(tot * (1.25 / 8388608.0)));
    }

    // ---- Phase 2: coalesced z write (one full 1024-float row per iter) ----
    for (int r = 0; r < TPB_TOKENS; ++r) {
        int k = ids_lds[r][w];  // wave-uniform
        float4 v = ((const float4*)(cb + (s * KC + k) * DSEG))[lane];
        ((float4*)(z_out + (tok_base + r) * D_FULL))[i] = v;
    }

    // ---- ids_packed (as float32 values) ----
    if (i < TPB_TOKENS) {
        int p = ids_lds[i][0] + 16 * ids_lds[i][1] + 256 * ids_lds[i][2] +
                4096 * ids_lds[i][3];
        ids_out[tok_base + i] = (float)p;
    }
}

extern "C" void kernel_launch(void* const* d_in, const int* in_sizes, int n_in,
                              void* d_out, int out_size, void* d_ws, size_t ws_size,
                              hipStream_t stream) {
    const float* h  = (const float*)d_in[0];
    const float* cb = (const float*)d_in[1];

    const int n_h = in_sizes[0];          // 33554432
    const int tokens = n_h / D_FULL;      // 32768

    float* z_out    = (float*)d_out;
    float* ids_out  = z_out + (size_t)n_h;
    float* loss_out = ids_out + tokens;

    double* cbd = (double*)d_ws;                  // 16384 doubles
    double* c2d = cbd + SEG * KC * DSEG;          // 64 doubles

    dvq_prep<<<1, 256, 0, stream>>>(cb, cbd, c2d, loss_out);
    dvq_main<<<tokens / TPB_TOKENS, 256, 0, stream>>>(h, cb, cbd, c2d, z_out,
                                                      ids_out, loss_out);
}